// Round 2
// baseline (606.554 us; speedup 1.0000x reference)
//
#include <hip/hip_runtime.h>
#include <math.h>

#define ROWS 65536
#define DIM  256
#define KC   1024
#define NQ   (ROWS * DIM)

// ---- ws layout (bytes) ----
// [0]      double lossacc
// [16]     int    counts[1024]        (ends 4112)
// [4224]   float  B32[1024]           (ends 8320)
// [8320]   float  Arr[65536]          (ends 270464)
// [270464] int    idx32[65536]        (ends 532608)

// ---------------------------------------------------------------------------
// numpy pairwise sum-of-squares for 256 contiguous fp32 (replicates
// numpy's scalar pairwise_sum: two 128-halves, 8 accumulators each,
// tree ((r0+r1)+(r2+r3))+((r4+r5)+(r6+r7)), halves added at the end).
// Products are rounded separately (Xf*Xf is an elementwise op in the ref),
// so use __fmul_rn + __fadd_rn (never contracted to fma).
// ---------------------------------------------------------------------------
__device__ __forceinline__ float sq_sum_numpy(const float* __restrict__ p) {
    float halves[2];
#pragma unroll
    for (int h = 0; h < 2; ++h) {
        const float* a = p + h * 128;
        float4 u0 = *(const float4*)(a);
        float4 u1 = *(const float4*)(a + 4);
        float r0 = __fmul_rn(u0.x, u0.x);
        float r1 = __fmul_rn(u0.y, u0.y);
        float r2 = __fmul_rn(u0.z, u0.z);
        float r3 = __fmul_rn(u0.w, u0.w);
        float r4 = __fmul_rn(u1.x, u1.x);
        float r5 = __fmul_rn(u1.y, u1.y);
        float r6 = __fmul_rn(u1.z, u1.z);
        float r7 = __fmul_rn(u1.w, u1.w);
        for (int i = 8; i < 128; i += 8) {
            float4 v0 = *(const float4*)(a + i);
            float4 v1 = *(const float4*)(a + i + 4);
            r0 = __fadd_rn(r0, __fmul_rn(v0.x, v0.x));
            r1 = __fadd_rn(r1, __fmul_rn(v0.y, v0.y));
            r2 = __fadd_rn(r2, __fmul_rn(v0.z, v0.z));
            r3 = __fadd_rn(r3, __fmul_rn(v0.w, v0.w));
            r4 = __fadd_rn(r4, __fmul_rn(v1.x, v1.x));
            r5 = __fadd_rn(r5, __fmul_rn(v1.y, v1.y));
            r6 = __fadd_rn(r6, __fmul_rn(v1.z, v1.z));
            r7 = __fadd_rn(r7, __fmul_rn(v1.w, v1.w));
        }
        float s01 = __fadd_rn(r0, r1);
        float s23 = __fadd_rn(r2, r3);
        float s45 = __fadd_rn(r4, r5);
        float s67 = __fadd_rn(r6, r7);
        halves[h] = __fadd_rn(__fadd_rn(s01, s23), __fadd_rn(s45, s67));
    }
    return __fadd_rn(halves[0], halves[1]);
}

// ---------------- K0a: codebook squared norms (fp32, numpy order) ----------
__global__ __launch_bounds__(256) void k_prepB(const float* __restrict__ E,
                                               float* __restrict__ B32) {
    int j = blockIdx.x * 256 + threadIdx.x;
    if (j >= KC) return;
    B32[j] = sq_sum_numpy(E + (size_t)j * DIM);
}

// ---------------- K0b: row squared norms (fp32, numpy order) ---------------
// One thread per row; lanes read stride-1KB but each 128B line is fully
// consumed over consecutive d within the lane -> L1-resident, no over-fetch.
__global__ __launch_bounds__(256) void k_prepA(const float* __restrict__ X,
                                               float* __restrict__ Arr) {
    int r = blockIdx.x * 256 + threadIdx.x;
    Arr[r] = sq_sum_numpy(X + (size_t)r * DIM);
}

// ---------------- K1: fp32 dist + first-index argmin -----------------------
// block = 256 threads; tile 128 rows x 128 cols; D staged in chunks of 32.
// acc[i][j] is a single fp32 fma chain over d = 0..255 ascending, from 0 --
// bit-identical to OpenBLAS sgemm's per-element accumulation (and x2 scaling
// commutes exactly with rounding, so 2*acc == (2X)@E^T bits).
#define TM 128
#define TN 128
#define TD 32
#define LSTR 132

__global__ __launch_bounds__(256) void k_pass1(
    const float* __restrict__ X, const float* __restrict__ E,
    const float* __restrict__ B32, const float* __restrict__ Arr,
    int* __restrict__ idx32)
{
    __shared__ float sm[2 * TD * LSTR];   // 33792 B; reused for merge at end
    float* Xs = sm;                 // [TD][LSTR]  (d-major, row minor)
    float* Es = sm + TD * LSTR;     // [TD][LSTR]  (d-major, col minor)

    const int tid = threadIdx.x;
    const int tx = tid & 15;        // col group (8 cols each)
    const int ty = tid >> 4;        // row group (8 rows each)
    const int rowbase = blockIdx.x * TM;

    float a8[8];
#pragma unroll
    for (int i = 0; i < 8; ++i) a8[i] = Arr[rowbase + ty * 8 + i];

    float v1[8]; int i1[8];
#pragma unroll
    for (int i = 0; i < 8; ++i) { v1[i] = 3.0e38f; i1[i] = 0; }

    for (int cb = 0; cb < KC; cb += TN) {
        float acc[8][8];
#pragma unroll
        for (int i = 0; i < 8; ++i)
#pragma unroll
            for (int j = 0; j < 8; ++j) acc[i][j] = 0.0f;

        for (int dc = 0; dc < DIM; dc += TD) {
            __syncthreads();
            // stage 128x32 of X and of E, transposed into LDS
#pragma unroll
            for (int k = 0; k < 4; ++k) {
                int fi  = tid + k * 256;          // 0..1023
                int r   = fi >> 3;                // 0..127
                int dd4 = (fi & 7) * 4;           // 0,4,...,28
                float4 xv = *(const float4*)(X + (size_t)(rowbase + r) * DIM + dc + dd4);
                Xs[(dd4 + 0) * LSTR + r] = xv.x;
                Xs[(dd4 + 1) * LSTR + r] = xv.y;
                Xs[(dd4 + 2) * LSTR + r] = xv.z;
                Xs[(dd4 + 3) * LSTR + r] = xv.w;
                float4 ev = *(const float4*)(E + (size_t)(cb + r) * DIM + dc + dd4);
                Es[(dd4 + 0) * LSTR + r] = ev.x;
                Es[(dd4 + 1) * LSTR + r] = ev.y;
                Es[(dd4 + 2) * LSTR + r] = ev.z;
                Es[(dd4 + 3) * LSTR + r] = ev.w;
            }
            __syncthreads();

#pragma unroll 8
            for (int dd = 0; dd < TD; ++dd) {
                float xr[8], er[8];
                float4 t0 = *(float4*)&Xs[dd * LSTR + ty * 8];
                float4 t1 = *(float4*)&Xs[dd * LSTR + ty * 8 + 4];
                xr[0]=t0.x; xr[1]=t0.y; xr[2]=t0.z; xr[3]=t0.w;
                xr[4]=t1.x; xr[5]=t1.y; xr[6]=t1.z; xr[7]=t1.w;
                float4 u0 = *(float4*)&Es[dd * LSTR + tx * 8];
                float4 u1 = *(float4*)&Es[dd * LSTR + tx * 8 + 4];
                er[0]=u0.x; er[1]=u0.y; er[2]=u0.z; er[3]=u0.w;
                er[4]=u1.x; er[5]=u1.y; er[6]=u1.z; er[7]=u1.w;
#pragma unroll
                for (int i = 0; i < 8; ++i)
#pragma unroll
                    for (int j = 0; j < 8; ++j)
                        acc[i][j] = fmaf(xr[i], er[j], acc[i][j]);
            }
        }

        // fold this col-block: dist = fl(fl(A + B) - 2*dot), numpy rounding.
#pragma unroll
        for (int j = 0; j < 8; ++j) {
            int c = cb + tx * 8 + j;
            float b = B32[c];
#pragma unroll
            for (int i = 0; i < 8; ++i) {
                float Cv = __fmul_rn(2.0f, acc[i][j]);
                float t1v = __fadd_rn(a8[i], b);
                float dv  = __fsub_rn(t1v, Cv);
                // strict < keeps first (lowest) index; c ascends per thread
                if (dv < v1[i]) { v1[i] = dv; i1[i] = c; }
            }
        }
    }

    // merge (val, idx) across the 16 col-group threads per row (via LDS)
    __syncthreads();
    float* Mv = sm;                        // [128][16] floats
    int*   Mi = (int*)(sm + 2048);         // [128][16] ints
#pragma unroll
    for (int i = 0; i < 8; ++i) {
        int r = ty * 8 + i;
        Mv[r * 16 + tx] = v1[i];
        Mi[r * 16 + tx] = i1[i];
    }
    __syncthreads();
    if (tid < TM) {
        int r = tid;
        float bv = Mv[r * 16];
        int   bi = Mi[r * 16];
        for (int t = 1; t < 16; ++t) {
            float av = Mv[r * 16 + t];
            int   ai = Mi[r * 16 + t];
            if (av < bv || (av == bv && ai < bi)) { bv = av; bi = ai; }
        }
        idx32[rowbase + r] = bi;
    }
}

// ---------------- K3: gather quantized + fp64 loss accumulation ----------------
__global__ __launch_bounds__(256) void k_out(
    const float* __restrict__ X, const float* __restrict__ E,
    const int* __restrict__ idx32, float* __restrict__ out0,
    double* __restrict__ lossacc)
{
    const int NF4 = NQ / 4;
    double s = 0.0;
    for (int g = blockIdx.x * blockDim.x + threadIdx.x; g < NF4;
         g += gridDim.x * blockDim.x) {
        int row = g >> 6;
        int d4  = g & 63;
        int j = idx32[row];
        float4 q = *(const float4*)(E + (size_t)j * DIM + d4 * 4);
        float4 x = *(const float4*)(X + (size_t)g * 4);
        *(float4*)(out0 + (size_t)g * 4) = q;
        double dx;
        dx = (double)q.x - (double)x.x; s = fma(dx, dx, s);
        dx = (double)q.y - (double)x.y; s = fma(dx, dx, s);
        dx = (double)q.z - (double)x.z; s = fma(dx, dx, s);
        dx = (double)q.w - (double)x.w; s = fma(dx, dx, s);
    }
#pragma unroll
    for (int off = 32; off > 0; off >>= 1) s += __shfl_down(s, off, 64);
    __shared__ double wsum[4];
    int lane = threadIdx.x & 63, wv = threadIdx.x >> 6;
    if (lane == 0) wsum[wv] = s;
    __syncthreads();
    if (threadIdx.x == 0) {
        double t = wsum[0] + wsum[1] + wsum[2] + wsum[3];
        atomicAdd(lossacc, t);
    }
}

// ---------------- K3b: index output + histogram ----------------
__global__ __launch_bounds__(256) void k_idxout(
    const int* __restrict__ idx32, float* __restrict__ out1,
    int* __restrict__ counts)
{
    __shared__ int h[KC];
    for (int i = threadIdx.x; i < KC; i += 256) h[i] = 0;
    __syncthreads();
    int r = blockIdx.x * 256 + threadIdx.x;   // grid 256*256 = 65536 exact
    int j = idx32[r];
    out1[r] = (float)j;
    atomicAdd(&h[j], 1);
    __syncthreads();
    for (int i = threadIdx.x; i < KC; i += 256)
        if (h[i]) atomicAdd(&counts[i], h[i]);
}

// ---------------- K4: perplexity + loss finalize ----------------
__global__ void k_fin(const int* __restrict__ counts,
                      const double* __restrict__ lossacc,
                      float* __restrict__ out_pl)
{
    __shared__ double sh[256];
    double s = 0.0;
    for (int i = threadIdx.x; i < KC; i += 256) {
        double p = (double)counts[i] / 65536.0;
        s += p * log(p + 1.1920928955078125e-07);   // EPS = fp32 eps exactly
    }
    sh[threadIdx.x] = s;
    __syncthreads();
    for (int off = 128; off > 0; off >>= 1) {
        if (threadIdx.x < off) sh[threadIdx.x] += sh[threadIdx.x + off];
        __syncthreads();
    }
    if (threadIdx.x == 0) {
        out_pl[0] = (float)exp(-sh[0]);
        out_pl[1] = (float)((*lossacc / (double)NQ) * 1.1);  // q + 0.1*e latent
    }
}

extern "C" void kernel_launch(void* const* d_in, const int* in_sizes, int n_in,
                              void* d_out, int out_size, void* d_ws, size_t ws_size,
                              hipStream_t stream) {
    const float* X = (const float*)d_in[0];
    const float* E = (const float*)d_in[1];
    float* out = (float*)d_out;
    char* ws = (char*)d_ws;

    double* lossacc = (double*)(ws + 0);
    int*    counts  = (int*)(ws + 16);
    float*  B32     = (float*)(ws + 4224);
    float*  Arr     = (float*)(ws + 8320);
    int*    idx32   = (int*)(ws + 270464);

    // zero lossacc + counts (B32/Arr fully overwritten by prep kernels)
    hipMemsetAsync(d_ws, 0, 4224, stream);

    hipLaunchKernelGGL(k_prepB, dim3(4),        dim3(256), 0, stream, E, B32);
    hipLaunchKernelGGL(k_prepA, dim3(256),      dim3(256), 0, stream, X, Arr);
    hipLaunchKernelGGL(k_pass1, dim3(ROWS / TM), dim3(256), 0, stream,
                       X, E, B32, Arr, idx32);
    hipLaunchKernelGGL(k_out,   dim3(2048),     dim3(256), 0, stream,
                       X, E, idx32, out, lossacc);
    hipLaunchKernelGGL(k_idxout, dim3(256),     dim3(256), 0, stream,
                       idx32, out + NQ, counts);
    hipLaunchKernelGGL(k_fin,   dim3(1),        dim3(256), 0, stream,
                       counts, lossacc, out + NQ + 65536);
}